// Round 4
// baseline (232.436 us; speedup 1.0000x reference)
//
#include <hip/hip_runtime.h>
#include <math.h>

// Problem shape (fixed by the reference): x is [B=8, S=4096, D=1024] fp32.
constexpr int B = 8;
constexpr int S = 4096;
constexpr int D = 1024;
constexpr int DQ = D / 4;            // float4 groups per row = 256
constexpr int DQ_SHIFT = 8;          // log2(DQ)
constexpr int PLANE4 = S * DQ;       // 2^20 float4 per [S,D] plane
constexpr int HALF4 = (B / 2) * PLANE4;  // threads cover batches 0..3; each also does b+4

// Native vector type — __builtin_nontemporal_store requires it (HIP float4 is a class).
typedef float vfloat4 __attribute__((ext_vector_type(4)));

// -log2(10000) / D
#define NEG_L2_10000_OVER_D (-13.287712379549449f / 1024.0f)

__global__ __launch_bounds__(256)
void pe_add_kernel(const float* __restrict__ x, float* __restrict__ out) {
    const int idx4 = blockIdx.x * blockDim.x + threadIdx.x;  // 0 .. HALF4-1

    const vfloat4* __restrict__ xv = (const vfloat4*)x;
    vfloat4* __restrict__ ov = (vfloat4*)out;

    // Two independent loads in flight (batches b and b+4, same plane offset).
    const size_t o0 = (size_t)idx4;
    const size_t o1 = (size_t)idx4 + (size_t)4 * PLANE4;
    vfloat4 v0 = xv[o0];
    vfloat4 v1 = xv[o1];

    const int pidx = idx4 & (PLANE4 - 1);   // position within the [S,D] plane
    const int dq   = pidx & (DQ - 1);
    const int s    = pidx >> DQ_SHIFT;
    const int d0   = dq << 2;

    const float fs = (float)s;
    const float a0 = fs * exp2f((float)(d0 + 0) * NEG_L2_10000_OVER_D);
    const float a1 = fs * exp2f((float)(d0 + 1) * NEG_L2_10000_OVER_D);
    const float a2 = fs * exp2f((float)(d0 + 2) * NEG_L2_10000_OVER_D);
    const float a3 = fs * exp2f((float)(d0 + 3) * NEG_L2_10000_OVER_D);

    vfloat4 pe;
    pe.x = __sinf(a0);   // even dim -> sin
    pe.y = __cosf(a1);   // odd  dim -> cos
    pe.z = __sinf(a2);
    pe.w = __cosf(a3);

    v0 += pe;
    v1 += pe;

    // Non-temporal: don't let the output stream evict x from L2/L3.
    __builtin_nontemporal_store(v0, &ov[o0]);
    __builtin_nontemporal_store(v1, &ov[o1]);
}

extern "C" void kernel_launch(void* const* d_in, const int* in_sizes, int n_in,
                              void* d_out, int out_size, void* d_ws, size_t ws_size,
                              hipStream_t stream) {
    const float* x = (const float*)d_in[0];
    float* out = (float*)d_out;

    const int threads = 256;
    const int blocks = HALF4 / threads;   // 16384
    pe_add_kernel<<<blocks, threads, 0, stream>>>(x, out);
}